// Round 23
// baseline (182.901 us; speedup 1.0000x reference)
//
#include <hip/hip_runtime.h>

namespace {
constexpr int NN  = 100000;   // nodes
constexpr int NE  = 1000000;  // edges
constexpr int INF = 256;
constexpr int HF  = 64;
constexpr int OF  = 16;
constexpr int SCAN_CHUNK = 1024;
constexpr int NBLK = (NN + SCAN_CHUNK - 1) / SCAN_CHUNK; // 98
constexpr int NSEG = 8;
constexpr int SEGW = (NN + NSEG - 1) / NSEG;             // 12500
constexpr int CNTW = 100096;
constexpr int ZBLK = (CNTW / 4 + 255) / 256;             // 98
constexpr int GB   = (NN + 127) / 128;                   // 782 gemm1 blocks
constexpr int ECHUNK = 2048;
constexpr int EGRP = (NE + ECHUNK - 1) / ECHUNK;         // 489
constexpr int SB   = EGRP * NSEG;                        // 3912 hist blocks
constexpr int SCB  = EGRP;                               // 489 scatter blocks
constexpr int CVB  = (NN * INF) / (256 * 16);            // 6250 conversion blocks

// ws layout offsets (4B units)
constexpr size_t OFF_dinv = 0;
constexpr size_t OFF_h1   = OFF_dinv + CNTW;                   // bf16 [NN*HF]
constexpr size_t OFF_h2   = OFF_h1 + (size_t)NN * HF / 2;      // bf16 [NN*OF]
constexpr size_t OFF_cnt  = OFF_h2 + (size_t)NN * OF / 2;
constexpr size_t OFF_rp   = OFF_cnt + CNTW;                    // rowptr [NN+1 pad]
constexpr size_t OFF_rank = OFF_rp + 100352;
constexpr size_t OFF_eidx = OFF_rank + (size_t)NE;
constexpr size_t OFF_bsum = OFF_eidx + (size_t)NE;
constexpr size_t OFF_wtg  = OFF_bsum + 128;                    // bf16 [64*256]
constexpr size_t OFF_xb   = OFF_wtg + 8192;                    // bf16 [NN*INF]
constexpr size_t NEED_XB  = (OFF_xb + (size_t)NN * INF / 2) * 4;  // bytes
}

typedef __attribute__((ext_vector_type(8))) short     sh8;
typedef __attribute__((ext_vector_type(4))) float     f32x4;
typedef __attribute__((ext_vector_type(8))) unsigned short us8;

__device__ __forceinline__ unsigned short f2bf(float f) {
    unsigned int u = __builtin_bit_cast(unsigned int, f);
    u += 0x7FFFu + ((u >> 16) & 1u);       // round-to-nearest-even
    return (unsigned short)(u >> 16);
}
__device__ __forceinline__ float bf2f(unsigned short s) {
    return __builtin_bit_cast(float, (unsigned int)s << 16);
}

// ---- pre: zero cnt + W1 -> bf16 transposed, one launch ---------------------
__global__ void k_pre(int* __restrict__ cnt, const float* __restrict__ W1,
                      unsigned short* __restrict__ wt_g) {
    int b = blockIdx.x, t = threadIdx.x;
    if (b < ZBLK) {
        int i = (b * 256 + t) * 4;
        if (i < CNTW) *(int4*)(cnt + i) = (int4){0, 0, 0, 0};
    } else {
        int idx = (b - ZBLK) * 256 + t;       // 16384 tasks
        int c = idx >> 8, k = idx & 255;
        wt_g[idx] = f2bf(W1[(size_t)k * HF + c]);
    }
}

// ---- shared hist body: 8 edges/thread, XCD-pinned segments, rank capture ---
__device__ __forceinline__ void hist_body(int hb, int t,
                                          const int* __restrict__ dst,
                                          int* __restrict__ cnt,
                                          int* __restrict__ rank) {
    int seg = hb & (NSEG - 1);
    int grp = hb >> 3;
    int e0  = grp * ECHUNK + t;
    int d[8];
    #pragma unroll
    for (int i = 0; i < 8; ++i) {
        int e = e0 + i * 256;
        d[i] = (e < NE) ? dst[e] : -1;
    }
    #pragma unroll
    for (int i = 0; i < 8; ++i) {
        if ((unsigned)d[i] / (unsigned)SEGW == (unsigned)seg)
            rank[e0 + i * 256] = atomicAdd(&cnt[d[i]], 1);
    }
}

// ---- FUSED: x->bf16 conversion (blocks 0..CVB-1) || hist (blocks CVB..) ----
// Conversion is a pure independent stream; hist is latency-bound with idle
// BW -> good overlap pairing. seg=(b-CVB)&7 stays bijective mod 8.
__global__ __launch_bounds__(256) void k_hc(const float* __restrict__ x,
                                            unsigned short* __restrict__ xb,
                                            const int* __restrict__ dst,
                                            int* __restrict__ cnt,
                                            int* __restrict__ rank) {
    int b = blockIdx.x, t = threadIdx.x;
    if (b < CVB) {
        size_t idx = ((size_t)b * 256 + t) * 16;
        float4 v0 = *(const float4*)(x + idx);
        float4 v1 = *(const float4*)(x + idx + 4);
        float4 v2 = *(const float4*)(x + idx + 8);
        float4 v3 = *(const float4*)(x + idx + 12);
        us8 lo = { f2bf(v0.x), f2bf(v0.y), f2bf(v0.z), f2bf(v0.w),
                   f2bf(v1.x), f2bf(v1.y), f2bf(v1.z), f2bf(v1.w) };
        us8 hi = { f2bf(v2.x), f2bf(v2.y), f2bf(v2.z), f2bf(v2.w),
                   f2bf(v3.x), f2bf(v3.y), f2bf(v3.z), f2bf(v3.w) };
        *(us8*)(xb + idx)     = lo;
        *(us8*)(xb + idx + 8) = hi;
        return;
    }
    hist_body(b - CVB, t, dst, cnt, rank);
}

// ---- standalone hist (fallback when ws too small for xb) -------------------
__global__ __launch_bounds__(256) void k_hist(const int* __restrict__ dst,
                                              int* __restrict__ cnt,
                                              int* __restrict__ rank) {
    hist_body(blockIdx.x, threadIdx.x, dst, cnt, rank);
}

// ---- block-reduce of cnt -> bsum, fused dinv = rsqrt(cnt+1) ----------------
__global__ __launch_bounds__(256) void k_reduce(const int* __restrict__ cnt,
                                                int* __restrict__ bsum,
                                                float* __restrict__ dinv) {
    int t = threadIdx.x;
    int i0 = blockIdx.x * SCAN_CHUNK + t * 4;
    int s = 0;
    float dv[4] = {0.f, 0.f, 0.f, 0.f};
    #pragma unroll
    for (int q = 0; q < 4; ++q) {
        if (i0 + q < NN) {
            int c = cnt[i0 + q];
            s += c;
            dv[q] = rsqrtf((float)(c + 1));
        }
    }
    if (i0 + 3 < NN) *(float4*)(dinv + i0) = (float4){dv[0], dv[1], dv[2], dv[3]};
    else { for (int q = 0; q < 4; ++q) if (i0 + q < NN) dinv[i0 + q] = dv[q]; }
    #pragma unroll
    for (int off = 32; off > 0; off >>= 1) s += __shfl_down(s, off);
    __shared__ int wsum[4];
    int lane = t & 63, wid = t >> 6;
    if (lane == 0) wsum[wid] = s;
    __syncthreads();
    if (t == 0) bsum[blockIdx.x] = wsum[0] + wsum[1] + wsum[2] + wsum[3];
}

// ---- scan: each block derives its own prefix from bsum ---------------------
__global__ __launch_bounds__(256) void k_scan(const int* __restrict__ cnt,
                                              const int* __restrict__ bsum,
                                              int* __restrict__ rowptr) {
    int t = threadIdx.x;
    int b = blockIdx.x;
    int lane = t & 63, wid = t >> 6;

    int p = 0;
    if (lane < b) p += bsum[lane];
    if (64 + lane < b) p += bsum[64 + lane];
    #pragma unroll
    for (int off = 32; off > 0; off >>= 1) p += __shfl_down(p, off);
    int blockBase = __shfl(p, 0);

    int i0 = b * SCAN_CHUNK + t * 4;
    int v0 = 0, v1 = 0, v2 = 0, v3 = 0;
    if (i0 + 0 < NN) v0 = cnt[i0 + 0];
    if (i0 + 1 < NN) v1 = cnt[i0 + 1];
    if (i0 + 2 < NN) v2 = cnt[i0 + 2];
    if (i0 + 3 < NN) v3 = cnt[i0 + 3];
    int tsum = v0 + v1 + v2 + v3;
    int incl = tsum;
    #pragma unroll
    for (int off = 1; off < 64; off <<= 1) {
        int n = __shfl_up(incl, off);
        if (lane >= off) incl += n;
    }
    __shared__ int wsum[4];
    if (lane == 63) wsum[wid] = incl;
    __syncthreads();
    int woff = 0;
    for (int w = 0; w < wid; ++w) woff += wsum[w];
    int excl = woff + (incl - tsum) + blockBase;
    int e0 = excl, e1 = e0 + v0, e2 = e1 + v1, e3 = e2 + v2;
    if (i0 + 0 < NN) rowptr[i0 + 0] = e0;
    if (i0 + 1 < NN) rowptr[i0 + 1] = e1;
    if (i0 + 2 < NN) rowptr[i0 + 2] = e2;
    if (i0 + 3 < NN) rowptr[i0 + 3] = e3;
    if (i0 + 3 == NN - 1) rowptr[NN] = e3 + v3;
}

// ---- shared scatter body (atomic-free) -------------------------------------
__device__ __forceinline__ void scatter_body(int sb, int t,
                                             const int* __restrict__ src,
                                             const int* __restrict__ dst,
                                             const int* __restrict__ rank,
                                             const int* __restrict__ rowptr,
                                             int* __restrict__ eidx) {
    int e0 = sb * ECHUNK + t;
    #pragma unroll
    for (int i = 0; i < 8; ++i) {
        int e = e0 + i * 256;
        if (e < NE) {
            int d = dst[e];
            eidx[rowptr[d] + rank[e]] = src[e];
        }
    }
}

// ---- FUSED: gemm1 from bf16 xb (blocks 0..GB-1) || scatter -----------------
// gemm1: barrier-free register path (R21 — fastest variant), but A-fragments
// are single 16B sh8 loads from pre-converted xb: HALF the x bytes, zero
// f2bf VALU in the hot loop. B-fragments from 32KB L1-resident wt_g.
__global__ __launch_bounds__(256, 8) void k_gs(const unsigned short* __restrict__ xb,
                                               const unsigned short* __restrict__ wt_g,
                                               unsigned short* __restrict__ h1,
                                               const int* __restrict__ src,
                                               const int* __restrict__ dst,
                                               const int* __restrict__ rank,
                                               const int* __restrict__ rowptr,
                                               int* __restrict__ eidx) {
    int b = blockIdx.x;
    int t = threadIdx.x;

    if (b >= GB) { scatter_body(b - GB, t, src, dst, rank, rowptr, eidx); return; }

    int w = t >> 6, l = t & 63;
    int row0 = b * 128;
    int m = l & 15;
    int g = l >> 4;
    int gr0 = row0 + w * 32 + m;      if (gr0 > NN - 1) gr0 = NN - 1;
    int gr1 = row0 + w * 32 + 16 + m; if (gr1 > NN - 1) gr1 = NN - 1;
    const unsigned short* xp0 = xb + (size_t)gr0 * INF + g * 8;
    const unsigned short* xp1 = xb + (size_t)gr1 * INF + g * 8;
    const unsigned short* wb0 = wt_g + (size_t)(0 * 16 + m) * 256 + g * 8;
    const unsigned short* wb1 = wt_g + (size_t)(1 * 16 + m) * 256 + g * 8;
    const unsigned short* wb2 = wt_g + (size_t)(2 * 16 + m) * 256 + g * 8;
    const unsigned short* wb3 = wt_g + (size_t)(3 * 16 + m) * 256 + g * 8;

    f32x4 acc[2][4];
    #pragma unroll
    for (int i = 0; i < 2; ++i)
        #pragma unroll
        for (int j = 0; j < 4; ++j) acc[i][j] = (f32x4){0.f, 0.f, 0.f, 0.f};

    #pragma unroll
    for (int kb = 0; kb < INF; kb += 32) {
        sh8 a0 = *(const sh8*)(xp0 + kb);
        sh8 a1 = *(const sh8*)(xp1 + kb);
        sh8 b0 = *(const sh8*)(wb0 + kb);
        sh8 b1 = *(const sh8*)(wb1 + kb);
        sh8 b2 = *(const sh8*)(wb2 + kb);
        sh8 b3 = *(const sh8*)(wb3 + kb);
        acc[0][0] = __builtin_amdgcn_mfma_f32_16x16x32_bf16(a0, b0, acc[0][0], 0, 0, 0);
        acc[1][0] = __builtin_amdgcn_mfma_f32_16x16x32_bf16(a1, b0, acc[1][0], 0, 0, 0);
        acc[0][1] = __builtin_amdgcn_mfma_f32_16x16x32_bf16(a0, b1, acc[0][1], 0, 0, 0);
        acc[1][1] = __builtin_amdgcn_mfma_f32_16x16x32_bf16(a1, b1, acc[1][1], 0, 0, 0);
        acc[0][2] = __builtin_amdgcn_mfma_f32_16x16x32_bf16(a0, b2, acc[0][2], 0, 0, 0);
        acc[1][2] = __builtin_amdgcn_mfma_f32_16x16x32_bf16(a1, b2, acc[1][2], 0, 0, 0);
        acc[0][3] = __builtin_amdgcn_mfma_f32_16x16x32_bf16(a0, b3, acc[0][3], 0, 0, 0);
        acc[1][3] = __builtin_amdgcn_mfma_f32_16x16x32_bf16(a1, b3, acc[1][3], 0, 0, 0);
    }

    #pragma unroll
    for (int mt = 0; mt < 2; ++mt) {
        #pragma unroll
        for (int r = 0; r < 4; ++r) {
            int gr = row0 + w * 32 + mt * 16 + (l >> 4) * 4 + r;
            if (gr < NN) {
                #pragma unroll
                for (int nt = 0; nt < 4; ++nt)
                    h1[(size_t)gr * HF + nt * 16 + (l & 15)] = f2bf(acc[mt][nt][r]);
            }
        }
    }
}

// ---- FALLBACK fused kernel: gemm1 from fp32 x || scatter (R22/R21 path) ----
__global__ __launch_bounds__(256, 8) void k_gs32(const float* __restrict__ x,
                                                 const unsigned short* __restrict__ wt_g,
                                                 unsigned short* __restrict__ h1,
                                                 const int* __restrict__ src,
                                                 const int* __restrict__ dst,
                                                 const int* __restrict__ rank,
                                                 const int* __restrict__ rowptr,
                                                 int* __restrict__ eidx) {
    int b = blockIdx.x;
    int t = threadIdx.x;
    if (b >= GB) { scatter_body(b - GB, t, src, dst, rank, rowptr, eidx); return; }

    int w = t >> 6, l = t & 63;
    int row0 = b * 128;
    int m = l & 15;
    int g = l >> 4;
    int gr0 = row0 + w * 32 + m;      if (gr0 > NN - 1) gr0 = NN - 1;
    int gr1 = row0 + w * 32 + 16 + m; if (gr1 > NN - 1) gr1 = NN - 1;
    const float* p0 = x + (size_t)gr0 * INF + g * 8;
    const float* p1 = x + (size_t)gr1 * INF + g * 8;
    const unsigned short* wb0 = wt_g + (size_t)(0 * 16 + m) * 256 + g * 8;
    const unsigned short* wb1 = wt_g + (size_t)(1 * 16 + m) * 256 + g * 8;
    const unsigned short* wb2 = wt_g + (size_t)(2 * 16 + m) * 256 + g * 8;
    const unsigned short* wb3 = wt_g + (size_t)(3 * 16 + m) * 256 + g * 8;

    f32x4 acc[2][4];
    #pragma unroll
    for (int i = 0; i < 2; ++i)
        #pragma unroll
        for (int j = 0; j < 4; ++j) acc[i][j] = (f32x4){0.f, 0.f, 0.f, 0.f};

    #pragma unroll
    for (int kb = 0; kb < INF; kb += 32) {
        float4 u0 = *(const float4*)(p0 + kb);
        float4 u1 = *(const float4*)(p0 + kb + 4);
        float4 u2 = *(const float4*)(p1 + kb);
        float4 u3 = *(const float4*)(p1 + kb + 4);
        sh8 b0 = *(const sh8*)(wb0 + kb);
        sh8 b1 = *(const sh8*)(wb1 + kb);
        sh8 b2 = *(const sh8*)(wb2 + kb);
        sh8 b3 = *(const sh8*)(wb3 + kb);
        us8 a0u = { f2bf(u0.x), f2bf(u0.y), f2bf(u0.z), f2bf(u0.w),
                    f2bf(u1.x), f2bf(u1.y), f2bf(u1.z), f2bf(u1.w) };
        us8 a1u = { f2bf(u2.x), f2bf(u2.y), f2bf(u2.z), f2bf(u2.w),
                    f2bf(u3.x), f2bf(u3.y), f2bf(u3.z), f2bf(u3.w) };
        sh8 a0 = __builtin_bit_cast(sh8, a0u);
        sh8 a1 = __builtin_bit_cast(sh8, a1u);
        acc[0][0] = __builtin_amdgcn_mfma_f32_16x16x32_bf16(a0, b0, acc[0][0], 0, 0, 0);
        acc[1][0] = __builtin_amdgcn_mfma_f32_16x16x32_bf16(a1, b0, acc[1][0], 0, 0, 0);
        acc[0][1] = __builtin_amdgcn_mfma_f32_16x16x32_bf16(a0, b1, acc[0][1], 0, 0, 0);
        acc[1][1] = __builtin_amdgcn_mfma_f32_16x16x32_bf16(a1, b1, acc[1][1], 0, 0, 0);
        acc[0][2] = __builtin_amdgcn_mfma_f32_16x16x32_bf16(a0, b2, acc[0][2], 0, 0, 0);
        acc[1][2] = __builtin_amdgcn_mfma_f32_16x16x32_bf16(a1, b2, acc[1][2], 0, 0, 0);
        acc[0][3] = __builtin_amdgcn_mfma_f32_16x16x32_bf16(a0, b3, acc[0][3], 0, 0, 0);
        acc[1][3] = __builtin_amdgcn_mfma_f32_16x16x32_bf16(a1, b3, acc[1][3], 0, 0, 0);
    }

    #pragma unroll
    for (int mt = 0; mt < 2; ++mt) {
        #pragma unroll
        for (int r = 0; r < 4; ++r) {
            int gr = row0 + w * 32 + mt * 16 + (l >> 4) * 4 + r;
            if (gr < NN) {
                #pragma unroll
                for (int nt = 0; nt < 4; ++nt)
                    h1[(size_t)gr * HF + nt * 16 + (l & 15)] = f2bf(acc[mt][nt][r]);
            }
        }
    }
}

// ---- Gather layer 1: 8 nodes/wave, 8 lanes/node, lane owns 8 feats ---------
__global__ __launch_bounds__(256) void k_gather1(const int* __restrict__ rowptr,
                                                 const int* __restrict__ eidx,
                                                 const float* __restrict__ dinv,
                                                 const unsigned short* __restrict__ h1,
                                                 const float* __restrict__ b1,
                                                 const float* __restrict__ W2,
                                                 unsigned short* __restrict__ h2) {
    __shared__ float w2L[HF * OF];     // 4KB, [k][j]
    __shared__ float hrL[32][HF + 4];  // 8.5KB, stride 68 (bank-spread)
    int t = threadIdx.x;
    *(float4*)(w2L + t * 4) = *(const float4*)(W2 + t * 4);

    int nodeL = t >> 3;
    int fg    = t & 7;
    int v     = blockIdx.x * 32 + nodeL;   // NN = 3125*32 exact
    int beg = rowptr[v], end = rowptr[v + 1];

    float acc[8] = {};
    int   s_n = 0;  float w_n = 0.f;  us8 h_n = {};
    if (beg < end) {
        s_n = eidx[beg];
        w_n = dinv[s_n];
        h_n = *(const us8*)(h1 + (size_t)s_n * HF + fg * 8);
    }
    for (int i = beg; i < end; ++i) {
        float w_c = w_n;  us8 h_c = h_n;
        if (i + 1 < end) {
            s_n = eidx[i + 1];
            w_n = dinv[s_n];
            h_n = *(const us8*)(h1 + (size_t)s_n * HF + fg * 8);
        }
        #pragma unroll
        for (int q = 0; q < 8; ++q) acc[q] += w_c * bf2f(h_c[q]);
    }

    {
        float dv = dinv[v], sl = dv * dv;
        us8 hv = *(const us8*)(h1 + (size_t)v * HF + fg * 8);
        #pragma unroll
        for (int q = 0; q < 8; ++q) {
            float val = dv * acc[q] + sl * bf2f(hv[q]) + b1[fg * 8 + q];
            hrL[nodeL][fg * 8 + q] = val > 0.f ? val : 0.f;
        }
    }
    __syncthreads();

    #pragma unroll
    for (int T = t; T < 512; T += 256) {
        int n = T >> 4, j = T & 15;
        const float* hr = hrL[n];
        float p = 0.f;
        #pragma unroll
        for (int k = 0; k < HF; ++k) p += hr[k] * w2L[k * OF + j];
        h2[(size_t)(blockIdx.x * 32 + n) * OF + j] = f2bf(p);
    }
}

// ---- Gather layer 2: 16 nodes/block, 16 lanes/node, lane owns 1 out-feat ---
__global__ __launch_bounds__(256) void k_gather2(const int* __restrict__ rowptr,
                                                 const int* __restrict__ eidx,
                                                 const float* __restrict__ dinv,
                                                 const unsigned short* __restrict__ h2,
                                                 const float* __restrict__ b2,
                                                 float* __restrict__ out) {
    int t     = threadIdx.x;
    int nodeL = t >> 4;
    int j     = t & 15;
    int v     = blockIdx.x * 16 + nodeL;   // NN = 6250*16 exact
    int beg = rowptr[v], end = rowptr[v + 1];

    float acc = 0.f;
    int   s_n = 0;  float w_n = 0.f;  unsigned short h_n = 0;
    if (beg < end) {
        s_n = eidx[beg];
        w_n = dinv[s_n];
        h_n = h2[(size_t)s_n * OF + j];
    }
    for (int i = beg; i < end; ++i) {
        float w_c = w_n;  unsigned short h_c = h_n;
        if (i + 1 < end) {
            s_n = eidx[i + 1];
            w_n = dinv[s_n];
            h_n = h2[(size_t)s_n * OF + j];
        }
        acc += w_c * bf2f(h_c);
    }
    float dv = dinv[v];
    out[(size_t)v * OF + j] = dv * acc + dv * dv * bf2f(h2[(size_t)v * OF + j]) + b2[j];
}

extern "C" void kernel_launch(void* const* d_in, const int* in_sizes, int n_in,
                              void* d_out, int out_size, void* d_ws, size_t ws_size,
                              hipStream_t stream) {
    const float* x   = (const float*)d_in[0];
    const int*   ei  = (const int*)d_in[1];
    const int*   src = ei;
    const int*   dst = ei + NE;
    const float* W1  = (const float*)d_in[2];
    const float* b1  = (const float*)d_in[3];
    const float* W2  = (const float*)d_in[4];
    const float* b2  = (const float*)d_in[5];
    float* out = (float*)d_out;

    int* ws = (int*)d_ws;
    float* dinv   = (float*)(ws + OFF_dinv);
    unsigned short* h1b = (unsigned short*)(ws + OFF_h1);
    unsigned short* h2b = (unsigned short*)(ws + OFF_h2);
    int*   cnt    = ws + OFF_cnt;
    int*   rowptr = ws + OFF_rp;
    int*   rank   = ws + OFF_rank;
    int*   eidx   = ws + OFF_eidx;
    int*   bsum   = ws + OFF_bsum;
    unsigned short* wt_g = (unsigned short*)(ws + OFF_wtg);
    unsigned short* xb   = (unsigned short*)(ws + OFF_xb);

    bool use_xb = ws_size >= NEED_XB;   // constant per-deployment -> deterministic

    k_pre<<<ZBLK + 64, 256, 0, stream>>>(cnt, W1, wt_g);

    if (use_xb) {
        // x->bf16 conversion || hist in one launch
        k_hc<<<CVB + SB, 256, 0, stream>>>(x, xb, dst, cnt, rank);
    } else {
        k_hist<<<SB, 256, 0, stream>>>(dst, cnt, rank);
    }

    k_reduce<<<NBLK, 256, 0, stream>>>(cnt, bsum, dinv);
    k_scan<<<NBLK, 256, 0, stream>>>(cnt, bsum, rowptr);

    if (use_xb) {
        k_gs<<<GB + SCB, 256, 0, stream>>>(xb, wt_g, h1b, src, dst, rank, rowptr, eidx);
    } else {
        k_gs32<<<GB + SCB, 256, 0, stream>>>(x, wt_g, h1b, src, dst, rank, rowptr, eidx);
    }

    k_gather1<<<NN / 32, 256, 0, stream>>>(rowptr, eidx, dinv, h1b, b1, W2, h2b);
    k_gather2<<<NN / 16, 256, 0, stream>>>(rowptr, eidx, dinv, h2b, b2, out);
}